// Round 7
// baseline (668.007 us; speedup 1.0000x reference)
//
#include <hip/hip_runtime.h>

// Problem constants (fixed by setup_inputs)
#define B_ 4
#define C_ 256
#define N_ 4096   // 64*64 spatial
#define D_ 8      // QK_DIM

typedef float f32x4 __attribute__((ext_vector_type(4)));
typedef __bf16 bf16x8 __attribute__((ext_vector_type(8)));

union U16 {
  bf16x8 v;
  unsigned short u[8];
  uint4 q;
};

__device__ inline unsigned short f2bf(float f) {
  unsigned int u = __float_as_uint(f);
  u = (u + 0x7FFFu + ((u >> 16) & 1u)) >> 16;  // RNE
  return (unsigned short)u;
}

// ---------------------------------------------------------------------------
// K1: pq[b][n][d] = Wq[d,:]·q[b,:,n] + bq[d]   (B,N,8) d-contiguous
//     pk[b][d][n] = Wk[d,:]·k[b,:,n] + bk[d]   (B,8,N) n-contiguous
// ---------------------------------------------------------------------------
__global__ void __launch_bounds__(256) k_pqk(
    const float* __restrict__ q, const float* __restrict__ k,
    const float* __restrict__ Wq, const float* __restrict__ bq,
    const float* __restrict__ Wk, const float* __restrict__ bk,
    float* __restrict__ pq_g, float* __restrict__ pk_g) {
  int b = blockIdx.y, n0 = blockIdx.x * 64;
  int t = threadIdx.x, nl = t & 63, sub = t >> 6;  // sub uniform per wave
  int n = n0 + nl;
  float aq[D_], ak[D_];
#pragma unroll
  for (int d = 0; d < D_; ++d) { aq[d] = 0.f; ak[d] = 0.f; }
  const float* qp = q + ((size_t)(b * C_ + sub * 64)) * N_ + n;
  const float* kp = k + ((size_t)(b * C_ + sub * 64)) * N_ + n;
  for (int cc = 0; cc < 64; ++cc) {
    int c = sub * 64 + cc;
    float qv = qp[(size_t)cc * N_];
    float kv = kp[(size_t)cc * N_];
#pragma unroll
    for (int d = 0; d < D_; ++d) {
      aq[d] = fmaf(Wq[d * C_ + c], qv, aq[d]);
      ak[d] = fmaf(Wk[d * C_ + c], kv, ak[d]);
    }
  }
  __shared__ float red[4][64][16];
#pragma unroll
  for (int d = 0; d < D_; ++d) { red[sub][nl][d] = aq[d]; red[sub][nl][8 + d] = ak[d]; }
  __syncthreads();
  if (t < 64) {
#pragma unroll
    for (int d = 0; d < D_; ++d) {
      float s = red[0][t][d] + red[1][t][d] + red[2][t][d] + red[3][t][d] + bq[d];
      pq_g[((size_t)b * N_ + n0 + t) * D_ + d] = s;
      float s2 = red[0][t][8 + d] + red[1][t][8 + d] + red[2][t][8 + d] + red[3][t][8 + d] + bk[d];
      pk_g[((size_t)b * D_ + d) * N_ + n0 + t] = s2;
    }
  }
}

// ---------------------------------------------------------------------------
// K2: pv[b][e][n] = Wv[e,:]·x[b,:,n] + bv[e], stored bf16 in (B,C,N).
// ---------------------------------------------------------------------------
__global__ void __launch_bounds__(256) k_pv(
    const float* __restrict__ x, const float* __restrict__ Wv,
    const float* __restrict__ bv, unsigned short* __restrict__ pv_g) {
  int b = blockIdx.y, n0 = blockIdx.x * 64;
  int t = threadIdx.x, lane = t & 63, w = t >> 6;
  __shared__ unsigned short xs[64][264];  // [n][c]
  {
    int nl = t & 63, sub = t >> 6;
    for (int i = 0; i < 64; ++i) {
      int c = i * 4 + sub;
      float xv = x[((size_t)(b * C_ + c)) * N_ + n0 + nl];
      xs[nl][c] = f2bf(xv);
    }
  }
  __syncthreads();
  int e0 = w * 64;
  f32x4 acc[4][4];
#pragma unroll
  for (int mf = 0; mf < 4; ++mf)
#pragma unroll
    for (int nf = 0; nf < 4; ++nf) acc[mf][nf] = (f32x4)0.f;

  int rsel = lane & 15, koff = (lane >> 4) * 8;
  for (int kc = 0; kc < 8; ++kc) {
    int cbase = kc * 32 + koff;
    U16 afr[4];
#pragma unroll
    for (int mf = 0; mf < 4; ++mf) {
      const float* wp = Wv + (size_t)(e0 + mf * 16 + rsel) * C_ + cbase;
      float4 w0 = *(const float4*)wp;
      float4 w1 = *(const float4*)(wp + 4);
      afr[mf].u[0] = f2bf(w0.x); afr[mf].u[1] = f2bf(w0.y);
      afr[mf].u[2] = f2bf(w0.z); afr[mf].u[3] = f2bf(w0.w);
      afr[mf].u[4] = f2bf(w1.x); afr[mf].u[5] = f2bf(w1.y);
      afr[mf].u[6] = f2bf(w1.z); afr[mf].u[7] = f2bf(w1.w);
    }
    U16 bfr[4];
#pragma unroll
    for (int nf = 0; nf < 4; ++nf)
      bfr[nf].q = *(const uint4*)&xs[nf * 16 + rsel][cbase];
#pragma unroll
    for (int mf = 0; mf < 4; ++mf)
#pragma unroll
      for (int nf = 0; nf < 4; ++nf)
        acc[mf][nf] = __builtin_amdgcn_mfma_f32_16x16x32_bf16(afr[mf].v, bfr[nf].v, acc[mf][nf], 0, 0, 0);
  }
  int rowsub = (lane >> 4) * 4;
#pragma unroll
  for (int mf = 0; mf < 4; ++mf) {
#pragma unroll
    for (int nf = 0; nf < 4; ++nf) {
      int n = n0 + nf * 16 + rsel;
#pragma unroll
      for (int j = 0; j < 4; ++j) {
        int e = e0 + mf * 16 + rowsub + j;
        float v = acc[mf][nf][j] + bv[e];
        pv_g[((size_t)(b * C_ + e)) * N_ + n] = f2bf(v);
      }
    }
  }
}

// ---------------------------------------------------------------------------
// K3: rinv[b][n] = 1 / sum_m exp(energy[b][n][m]).  (two-pass exact softmax;
// |e| <= ~13 so exp is fp32-safe without max subtraction)
// ---------------------------------------------------------------------------
__global__ void __launch_bounds__(256) k_rowsum(
    const float* __restrict__ pq_g, const float* __restrict__ pk_g,
    float* __restrict__ rinv_g) {
  int b = blockIdx.y, n0 = blockIdx.x * 32;
  int t = threadIdx.x, lane = t & 63, w = t >> 6;
  int r0 = n0 + w * 8;
  float pqr[8][D_];
#pragma unroll
  for (int r = 0; r < 8; ++r) {
    const float4* pp = (const float4*)(pq_g + ((size_t)b * N_ + r0 + r) * D_);
    float4 a = pp[0], c4 = pp[1];
    pqr[r][0] = a.x; pqr[r][1] = a.y; pqr[r][2] = a.z; pqr[r][3] = a.w;
    pqr[r][4] = c4.x; pqr[r][5] = c4.y; pqr[r][6] = c4.z; pqr[r][7] = c4.w;
  }
  float s[8];
#pragma unroll
  for (int r = 0; r < 8; ++r) s[r] = 0.f;
  const float* pkb = pk_g + (size_t)b * D_ * N_;
  for (int tt = 0; tt < 64; ++tt) {
    int m = tt * 64 + lane;
    float pkr[D_];
#pragma unroll
    for (int d = 0; d < D_; ++d) pkr[d] = pkb[(size_t)d * N_ + m];
#pragma unroll
    for (int r = 0; r < 8; ++r) {
      float e = pqr[r][0] * pkr[0];
#pragma unroll
      for (int d = 1; d < D_; ++d) e = fmaf(pqr[r][d], pkr[d], e);
      s[r] += __expf(e);
    }
  }
#pragma unroll
  for (int r = 0; r < 8; ++r) {
    float v = s[r];
    for (int off = 32; off; off >>= 1) v += __shfl_xor(v, off);
    s[r] = v;
  }
  if (lane == 0) {
#pragma unroll
    for (int r = 0; r < 8; ++r) rinv_g[(size_t)b * N_ + r0 + r] = 1.0f / s[r];
  }
}

// ---------------------------------------------------------------------------
// K4 (m-chunked, 2x parallelism): grid 1024 blocks = 4/CU = 16 waves/CU.
// Block = (b, 32-row group, m-chunk of 2048). Iterates 32 m-tiles of 64.
// Phase A: wave w computes attn rows w*8..+8, lane=m (coalesced pk loads +
// coalesced NT fp32 attention stores + bf16 to asl). Phase B: wave w MFMAs
// 32 rows x 64 c with B-frags from LDS-staged pv (single buffer, loads for
// t+1 issued at iter top, ds_write after barrier 2; XOR slot-swizzle on the
// GLOBAL source keeps LDS writes linear & frag reads 2-way-conflict only).
// PV partial sums combined via fp32 atomicAdd into out_g pre-filled with x
// (async D2D copy). XCD pinning: combo=(b,rowhalf)=bx&7 so both chunks of
// the same rows share an XCD (atomic locality; pv+pk L2-resident).
// ---------------------------------------------------------------------------
__global__ void __launch_bounds__(256, 4) k_attn_out(
    const float* __restrict__ pq_g, const float* __restrict__ pk_g,
    const float* __restrict__ rinv_g, const unsigned short* __restrict__ pv_g,
    const float* __restrict__ gamma,
    float* __restrict__ out_g, float* __restrict__ attn_g) {
  int bx = blockIdx.x;             // 0..1023
  int combo = bx & 7;              // (b, rowhalf) -> XCD
  int b = combo >> 1, rh = combo & 1;
  int rest = bx >> 3;              // 0..127
  int chunk = rest >> 6;           // 0..1  (m-chunk)
  int grplow = rest & 63;
  int rowbase = rh * 2048 + grplow * 32;
  int mbase = chunk * 2048;

  int t = threadIdx.x, lane = t & 63, w = t >> 6;
  int r0 = rowbase + w * 8;        // phase-A rows for this wave
  int rsel = lane & 15, g = lane >> 4, koff = g * 8;
  int c0 = w * 64;                 // wave's MFMA c-slice == its staged rows

  __shared__ unsigned short pvs[256][64];  // 32KB, slot-swizzled content
  __shared__ unsigned short asl[32][72];   // attn bf16 [row][m], pad 72

  // phase-A per-wave row data (uniform addresses -> scalar loads)
  float pqr[8][D_], rinv[8];
#pragma unroll
  for (int rr = 0; rr < 8; ++rr) {
    const float4* pp = (const float4*)(pq_g + ((size_t)b * N_ + r0 + rr) * D_);
    float4 a = pp[0], c4 = pp[1];
    pqr[rr][0] = a.x; pqr[rr][1] = a.y; pqr[rr][2] = a.z; pqr[rr][3] = a.w;
    pqr[rr][4] = c4.x; pqr[rr][5] = c4.y; pqr[rr][6] = c4.z; pqr[rr][7] = c4.w;
    rinv[rr] = rinv_g[(size_t)b * N_ + r0 + rr];
  }

  f32x4 acc[2][4];
#pragma unroll
  for (int mf = 0; mf < 2; ++mf)
#pragma unroll
    for (int cf = 0; cf < 4; ++cf) acc[mf][cf] = (f32x4)0.f;

  const float* pkb = pk_g + (size_t)b * D_ * N_;
  const unsigned short* pvb = pv_g + (size_t)b * C_ * N_;
  float* attb = attn_g + ((size_t)b * N_ + r0) * N_;

  // staging geometry: wave w stages c-rows w*64..w*64+63.
  // LDS row c slot s (16B) holds global m-slot (s ^ (c&7)).
  int scs = w * 64 + (lane >> 3);  // + i*8
  int ss = lane & 7;

  // prologue: stage tile 0
  uint4 sreg[8];
#pragma unroll
  for (int i = 0; i < 8; ++i) {
    int c = scs + i * 8;
    sreg[i] = *(const uint4*)(pvb + (size_t)c * N_ + mbase + ((ss ^ (c & 7)) << 3));
  }
#pragma unroll
  for (int i = 0; i < 8; ++i) {
    int c = scs + i * 8;
    *(uint4*)&pvs[c][ss * 8] = sreg[i];
  }

  for (int tt = 0; tt < 32; ++tt) {
    int m0 = mbase + tt * 64;
    bool more = (tt + 1 < 32);
    // ---- issue next-tile pv loads (hidden under phase A + MFMA) ----
    if (more) {
#pragma unroll
      for (int i = 0; i < 8; ++i) {
        int c = scs + i * 8;
        sreg[i] = *(const uint4*)(pvb + (size_t)c * N_ + m0 + 64 + ((ss ^ (c & 7)) << 3));
      }
    }
    // ---- phase A: attn rows r0..r0+8, m = m0+lane (coalesced) ----
    {
      float pkr[D_];
#pragma unroll
      for (int d = 0; d < D_; ++d) pkr[d] = pkb[(size_t)d * N_ + m0 + lane];
#pragma unroll
      for (int rr = 0; rr < 8; ++rr) {
        float e = pqr[rr][0] * pkr[0];
#pragma unroll
        for (int d = 1; d < D_; ++d) e = fmaf(pqr[rr][d], pkr[d], e);
        float a = __expf(e) * rinv[rr];
        __builtin_nontemporal_store(a, attb + (size_t)rr * N_ + m0 + lane);
        asl[w * 8 + rr][lane] = f2bf(a);
      }
    }
    __syncthreads();  // asl ready; pvs(t) ready (written before prev barrier)
    // ---- phase B: MFMA 32 rows x 64 c over K=64 ----
    {
      U16 afr[2][2], bfr[2][4];
#pragma unroll
      for (int kf = 0; kf < 2; ++kf) {
#pragma unroll
        for (int mf = 0; mf < 2; ++mf)
          afr[kf][mf].q = *(const uint4*)&asl[mf * 16 + rsel][kf * 32 + koff];
#pragma unroll
        for (int cf = 0; cf < 4; ++cf) {
          int c = c0 + cf * 16 + rsel;
          int sg = kf * 4 + g;  // global m-slot within tile
          bfr[kf][cf].q = *(const uint4*)&pvs[c][((sg ^ (c & 7)) * 8)];
        }
      }
#pragma unroll
      for (int kf = 0; kf < 2; ++kf)
#pragma unroll
        for (int mf = 0; mf < 2; ++mf)
#pragma unroll
          for (int cf = 0; cf < 4; ++cf)
            acc[mf][cf] = __builtin_amdgcn_mfma_f32_16x16x32_bf16(
                afr[kf][mf].v, bfr[kf][cf].v, acc[mf][cf], 0, 0, 0);
    }
    __syncthreads();  // all waves done reading pvs(t) + asl
    // ---- write staged regs for tile t+1 (visible at next barrier 1) ----
    if (more) {
#pragma unroll
      for (int i = 0; i < 8; ++i) {
        int c = scs + i * 8;
        *(uint4*)&pvs[c][ss * 8] = sreg[i];
      }
    }
  }
  // epilogue: out_g (pre-filled with x) += gamma * partial_acc
  float gm = gamma[0];
  int rowsub = g * 4;
#pragma unroll
  for (int mf = 0; mf < 2; ++mf) {
#pragma unroll
    for (int cf = 0; cf < 4; ++cf) {
      int c = c0 + cf * 16 + rsel;
      int nrow = rowbase + mf * 16 + rowsub;
      float* op = out_g + ((size_t)(b * C_ + c)) * N_ + nrow;
#pragma unroll
      for (int j = 0; j < 4; ++j)
        atomicAdd(op + j, gm * acc[mf][cf][j]);
    }
  }
}

extern "C" void kernel_launch(void* const* d_in, const int* in_sizes, int n_in,
                              void* d_out, int out_size, void* d_ws, size_t ws_size,
                              hipStream_t stream) {
  const float* x  = (const float*)d_in[0];
  const float* k  = (const float*)d_in[1];
  const float* q  = (const float*)d_in[2];
  const float* Wq = (const float*)d_in[3];
  const float* bq = (const float*)d_in[4];
  const float* Wk = (const float*)d_in[5];
  const float* bk = (const float*)d_in[6];
  const float* Wv = (const float*)d_in[7];
  const float* bv = (const float*)d_in[8];
  const float* gamma = (const float*)d_in[9];

  float* out_g  = (float*)d_out;
  float* attn_g = out_g + (size_t)B_ * C_ * N_;  // attention starts after out

  // workspace layout (~9.2 MB): pq 512KB | pk 512KB | rinv 64KB | pv 8MB
  char* ws = (char*)d_ws;
  float* pq_g = (float*)ws;
  float* pk_g = (float*)(ws + (1u << 19));
  float* rinv_g = (float*)(ws + (1u << 20));
  unsigned short* pv_g = (unsigned short*)(ws + (1u << 20) + (1u << 17));

  k_pqk<<<dim3(64, B_), 256, 0, stream>>>(q, k, Wq, bq, Wk, bk, pq_g, pk_g);
  k_pv<<<dim3(64, B_), 256, 0, stream>>>(x, Wv, bv, pv_g);
  k_rowsum<<<dim3(128, B_), 256, 0, stream>>>(pq_g, pk_g, rinv_g);
  // pre-fill out = x, then K4 atomically accumulates gamma * (pv @ attn^T)
  hipMemcpyAsync(out_g, x, (size_t)B_ * C_ * N_ * sizeof(float),
                 hipMemcpyDeviceToDevice, stream);
  k_attn_out<<<dim3(1024), 256, 0, stream>>>(pq_g, pk_g, rinv_g, pv_g, gamma, out_g, attn_g);
}

// Round 9
// 419.422 us; speedup vs baseline: 1.5927x; 1.5927x over previous
//
#include <hip/hip_runtime.h>

// Problem constants (fixed by setup_inputs)
#define B_ 4
#define C_ 256
#define N_ 4096   // 64*64 spatial
#define D_ 8      // QK_DIM

typedef float f32x4 __attribute__((ext_vector_type(4)));
typedef __bf16 bf16x8 __attribute__((ext_vector_type(8)));

union U16 {
  bf16x8 v;
  unsigned short u[8];
  uint4 q;
};

__device__ inline unsigned short f2bf(float f) {
  unsigned int u = __float_as_uint(f);
  u = (u + 0x7FFFu + ((u >> 16) & 1u)) >> 16;  // RNE
  return (unsigned short)u;
}

// ---------------------------------------------------------------------------
// K1: pq[b][n][d] = Wq[d,:]·q[b,:,n] + bq[d]   (B,N,8) d-contiguous
//     pk[b][d][n] = Wk[d,:]·k[b,:,n] + bk[d]   (B,8,N) n-contiguous
// ---------------------------------------------------------------------------
__global__ void __launch_bounds__(256) k_pqk(
    const float* __restrict__ q, const float* __restrict__ k,
    const float* __restrict__ Wq, const float* __restrict__ bq,
    const float* __restrict__ Wk, const float* __restrict__ bk,
    float* __restrict__ pq_g, float* __restrict__ pk_g) {
  int b = blockIdx.y, n0 = blockIdx.x * 64;
  int t = threadIdx.x, nl = t & 63, sub = t >> 6;  // sub uniform per wave
  int n = n0 + nl;
  float aq[D_], ak[D_];
#pragma unroll
  for (int d = 0; d < D_; ++d) { aq[d] = 0.f; ak[d] = 0.f; }
  const float* qp = q + ((size_t)(b * C_ + sub * 64)) * N_ + n;
  const float* kp = k + ((size_t)(b * C_ + sub * 64)) * N_ + n;
  for (int cc = 0; cc < 64; ++cc) {
    int c = sub * 64 + cc;
    float qv = qp[(size_t)cc * N_];
    float kv = kp[(size_t)cc * N_];
#pragma unroll
    for (int d = 0; d < D_; ++d) {
      aq[d] = fmaf(Wq[d * C_ + c], qv, aq[d]);
      ak[d] = fmaf(Wk[d * C_ + c], kv, ak[d]);
    }
  }
  __shared__ float red[4][64][16];
#pragma unroll
  for (int d = 0; d < D_; ++d) { red[sub][nl][d] = aq[d]; red[sub][nl][8 + d] = ak[d]; }
  __syncthreads();
  if (t < 64) {
#pragma unroll
    for (int d = 0; d < D_; ++d) {
      float s = red[0][t][d] + red[1][t][d] + red[2][t][d] + red[3][t][d] + bq[d];
      pq_g[((size_t)b * N_ + n0 + t) * D_ + d] = s;
      float s2 = red[0][t][8 + d] + red[1][t][8 + d] + red[2][t][8 + d] + red[3][t][8 + d] + bk[d];
      pk_g[((size_t)b * D_ + d) * N_ + n0 + t] = s2;
    }
  }
}

// ---------------------------------------------------------------------------
// K2: pv[b][e][n] = Wv[e,:]·x[b,:,n] + bv[e], stored bf16 in (B,C,N).
// ---------------------------------------------------------------------------
__global__ void __launch_bounds__(256) k_pv(
    const float* __restrict__ x, const float* __restrict__ Wv,
    const float* __restrict__ bv, unsigned short* __restrict__ pv_g) {
  int b = blockIdx.y, n0 = blockIdx.x * 64;
  int t = threadIdx.x, lane = t & 63, w = t >> 6;
  __shared__ unsigned short xs[64][264];  // [n][c]
  {
    int nl = t & 63, sub = t >> 6;
    for (int i = 0; i < 64; ++i) {
      int c = i * 4 + sub;
      float xv = x[((size_t)(b * C_ + c)) * N_ + n0 + nl];
      xs[nl][c] = f2bf(xv);
    }
  }
  __syncthreads();
  int e0 = w * 64;
  f32x4 acc[4][4];
#pragma unroll
  for (int mf = 0; mf < 4; ++mf)
#pragma unroll
    for (int nf = 0; nf < 4; ++nf) acc[mf][nf] = (f32x4)0.f;

  int rsel = lane & 15, koff = (lane >> 4) * 8;
  for (int kc = 0; kc < 8; ++kc) {
    int cbase = kc * 32 + koff;
    U16 afr[4];
#pragma unroll
    for (int mf = 0; mf < 4; ++mf) {
      const float* wp = Wv + (size_t)(e0 + mf * 16 + rsel) * C_ + cbase;
      float4 w0 = *(const float4*)wp;
      float4 w1 = *(const float4*)(wp + 4);
      afr[mf].u[0] = f2bf(w0.x); afr[mf].u[1] = f2bf(w0.y);
      afr[mf].u[2] = f2bf(w0.z); afr[mf].u[3] = f2bf(w0.w);
      afr[mf].u[4] = f2bf(w1.x); afr[mf].u[5] = f2bf(w1.y);
      afr[mf].u[6] = f2bf(w1.z); afr[mf].u[7] = f2bf(w1.w);
    }
    U16 bfr[4];
#pragma unroll
    for (int nf = 0; nf < 4; ++nf)
      bfr[nf].q = *(const uint4*)&xs[nf * 16 + rsel][cbase];
#pragma unroll
    for (int mf = 0; mf < 4; ++mf)
#pragma unroll
      for (int nf = 0; nf < 4; ++nf)
        acc[mf][nf] = __builtin_amdgcn_mfma_f32_16x16x32_bf16(afr[mf].v, bfr[nf].v, acc[mf][nf], 0, 0, 0);
  }
  int rowsub = (lane >> 4) * 4;
#pragma unroll
  for (int mf = 0; mf < 4; ++mf) {
#pragma unroll
    for (int nf = 0; nf < 4; ++nf) {
      int n = n0 + nf * 16 + rsel;
#pragma unroll
      for (int j = 0; j < 4; ++j) {
        int e = e0 + mf * 16 + rowsub + j;
        float v = acc[mf][nf][j] + bv[e];
        pv_g[((size_t)(b * C_ + e)) * N_ + n] = f2bf(v);
      }
    }
  }
}

// ---------------------------------------------------------------------------
// K3 (fused rowsum + attention store): block = 8 rows x full m; wave w owns
// m-quarter w*1024..+1024. NO barriers in the m loops. Pass 1: per-wave
// partial rowsums of exp(e); LDS cross-wave reduce -> rinv. Pass 2:
// recompute exp, scale, coalesced NT fp32 store of attention.
// pq loads are block-uniform -> SGPRs (low VGPR, high occupancy).
// grid 2048 = 4b x 512 row-groups; b = bx&3 pins pk(b) per XCD.
// ---------------------------------------------------------------------------
__global__ void __launch_bounds__(256, 4) k_attn(
    const float* __restrict__ pq_g, const float* __restrict__ pk_g,
    float* __restrict__ attn_g) {
  int bx = blockIdx.x;
  int b = bx & 3;
  int rg = bx >> 2;            // 0..511
  int r0 = rg * 8;
  int t = threadIdx.x, lane = t & 63, w = t >> 6;
  int mq = w * 1024;           // wave's m-quarter

  // block-uniform pq rows -> scalar loads
  float pqr[8][D_];
#pragma unroll
  for (int rr = 0; rr < 8; ++rr) {
    const float4* pp = (const float4*)(pq_g + ((size_t)b * N_ + r0 + rr) * D_);
    float4 a = pp[0], c4 = pp[1];
    pqr[rr][0] = a.x; pqr[rr][1] = a.y; pqr[rr][2] = a.z; pqr[rr][3] = a.w;
    pqr[rr][4] = c4.x; pqr[rr][5] = c4.y; pqr[rr][6] = c4.z; pqr[rr][7] = c4.w;
  }
  const float* pkb = pk_g + (size_t)b * D_ * N_;

  // ---- pass 1: partial rowsums over this wave's quarter ----
  float s[8];
#pragma unroll
  for (int rr = 0; rr < 8; ++rr) s[rr] = 0.f;
  for (int tt = 0; tt < 16; ++tt) {
    int m = mq + tt * 64 + lane;
    float pkr[D_];
#pragma unroll
    for (int d = 0; d < D_; ++d) pkr[d] = pkb[(size_t)d * N_ + m];
#pragma unroll
    for (int rr = 0; rr < 8; ++rr) {
      float e = pqr[rr][0] * pkr[0];
#pragma unroll
      for (int d = 1; d < D_; ++d) e = fmaf(pqr[rr][d], pkr[d], e);
      s[rr] += __expf(e);
    }
  }
#pragma unroll
  for (int rr = 0; rr < 8; ++rr) {
    float v = s[rr];
    for (int off = 32; off; off >>= 1) v += __shfl_xor(v, off);
    s[rr] = v;
  }
  __shared__ float red[4][8];
  if (lane == 0) {
#pragma unroll
    for (int rr = 0; rr < 8; ++rr) red[w][rr] = s[rr];
  }
  __syncthreads();
  float rinv[8];
#pragma unroll
  for (int rr = 0; rr < 8; ++rr)
    rinv[rr] = 1.0f / (red[0][rr] + red[1][rr] + red[2][rr] + red[3][rr]);

  // ---- pass 2: normalize + NT store (coalesced 256B/row-instruction) ----
  float* attb = attn_g + ((size_t)b * N_ + r0) * N_;
  for (int tt = 0; tt < 16; ++tt) {
    int m = mq + tt * 64 + lane;
    float pkr[D_];
#pragma unroll
    for (int d = 0; d < D_; ++d) pkr[d] = pkb[(size_t)d * N_ + m];
#pragma unroll
    for (int rr = 0; rr < 8; ++rr) {
      float e = pqr[rr][0] * pkr[0];
#pragma unroll
      for (int d = 1; d < D_; ++d) e = fmaf(pqr[rr][d], pkr[d], e);
      float a = __expf(e) * rinv[rr];
      __builtin_nontemporal_store(a, attb + (size_t)rr * N_ + m);
    }
  }
}

// ---------------------------------------------------------------------------
// K4 (pure GEMM): out[b][c][n] = gamma * sum_m pv[c][m]*attn[n][m] + x[c][n].
// Reads fp32 attention back from d_out (read-once, NT loads), cvt to bf16 on
// stage. Block = 32 n x 256 c (wave w: c-slice w*64, staged pv rows = same).
// K loop over 64 m-tiles of 64: prefetch next attn+pv to regs, barrier,
// MFMA from LDS, barrier, write regs->LDS. pv slot-XOR-swizzled (round-6
// verified). grid 512 = 4b x 128 groups; b = bx&3 pins pv(b) per XCD.
// ---------------------------------------------------------------------------
__global__ void __launch_bounds__(256, 2) k_out(
    const float* __restrict__ attn_g, const unsigned short* __restrict__ pv_g,
    const float* __restrict__ x, const float* __restrict__ gamma,
    float* __restrict__ out_g) {
  int bx = blockIdx.x;
  int b = bx & 3, grp = bx >> 2;
  int n0 = grp * 32;
  int t = threadIdx.x, lane = t & 63, w = t >> 6;
  int rsel = lane & 15, g = lane >> 4, koff = g * 8;
  int c0 = w * 64;

  __shared__ unsigned short pvs[256][64];  // 32KB, slot-swizzled content
  __shared__ unsigned short asl[32][72];   // attn bf16 [row][m], pad 72

  const unsigned short* pvb = pv_g + (size_t)b * C_ * N_;
  const float* attb = attn_g + ((size_t)b * N_ + n0) * N_;

  // pv staging geometry: wave w stages c-rows w*64..+64.
  int scs = w * 64 + (lane >> 3);  // + i*8
  int ss = lane & 7;
  // attn staging geometry: thread t loads 8 floats of row arow at aseg*8.
  int arow = t >> 3, aseg = t & 7;
  const float* ap = attb + (size_t)arow * N_ + aseg * 8;

  f32x4 acc[2][4];
#pragma unroll
  for (int mf = 0; mf < 2; ++mf)
#pragma unroll
    for (int cf = 0; cf < 4; ++cf) acc[mf][cf] = (f32x4)0.f;

  // prologue: load tile 0 -> regs -> LDS
  uint4 sreg[8];
  f32x4 ar0, ar1;
#pragma unroll
  for (int i = 0; i < 8; ++i) {
    int c = scs + i * 8;
    sreg[i] = *(const uint4*)(pvb + (size_t)c * N_ + ((ss ^ (c & 7)) << 3));
  }
  ar0 = __builtin_nontemporal_load((const f32x4*)ap);
  ar1 = __builtin_nontemporal_load((const f32x4*)(ap + 4));
#pragma unroll
  for (int i = 0; i < 8; ++i) {
    int c = scs + i * 8;
    *(uint4*)&pvs[c][ss * 8] = sreg[i];
  }
  {
    U16 au;
#pragma unroll
    for (int j = 0; j < 4; ++j) { au.u[j] = f2bf(ar0[j]); au.u[4 + j] = f2bf(ar1[j]); }
    *(uint4*)&asl[arow][aseg * 8] = au.q;
  }

  for (int tt = 0; tt < 64; ++tt) {
    int m0 = tt * 64;
    bool more = (tt + 1 < 64);
    __syncthreads();  // LDS tile tt visible
    // ---- issue tile tt+1 loads (land by barrier 2) ----
    if (more) {
#pragma unroll
      for (int i = 0; i < 8; ++i) {
        int c = scs + i * 8;
        sreg[i] = *(const uint4*)(pvb + (size_t)c * N_ + m0 + 64 + ((ss ^ (c & 7)) << 3));
      }
      ar0 = __builtin_nontemporal_load((const f32x4*)(ap + m0 + 64));
      ar1 = __builtin_nontemporal_load((const f32x4*)(ap + m0 + 68));
    }
    // ---- MFMA: 32 n x 64 c over K=64 ----
    {
      U16 afr[2][2], bfr[2][4];
#pragma unroll
      for (int kf = 0; kf < 2; ++kf) {
#pragma unroll
        for (int mf = 0; mf < 2; ++mf)
          afr[kf][mf].q = *(const uint4*)&asl[mf * 16 + rsel][kf * 32 + koff];
#pragma unroll
        for (int cf = 0; cf < 4; ++cf) {
          int c = c0 + cf * 16 + rsel;
          int sg = kf * 4 + g;  // global m-slot within tile
          bfr[kf][cf].q = *(const uint4*)&pvs[c][((sg ^ (c & 7)) * 8)];
        }
      }
#pragma unroll
      for (int kf = 0; kf < 2; ++kf)
#pragma unroll
        for (int mf = 0; mf < 2; ++mf)
#pragma unroll
          for (int cf = 0; cf < 4; ++cf)
            acc[mf][cf] = __builtin_amdgcn_mfma_f32_16x16x32_bf16(
                afr[kf][mf].v, bfr[kf][cf].v, acc[mf][cf], 0, 0, 0);
    }
    __syncthreads();  // reads done; tt+1 loads drained
    if (more) {
#pragma unroll
      for (int i = 0; i < 8; ++i) {
        int c = scs + i * 8;
        *(uint4*)&pvs[c][ss * 8] = sreg[i];
      }
      U16 au;
#pragma unroll
      for (int j = 0; j < 4; ++j) { au.u[j] = f2bf(ar0[j]); au.u[4 + j] = f2bf(ar1[j]); }
      *(uint4*)&asl[arow][aseg * 8] = au.q;
    }
  }
  // epilogue: out = gamma*acc + x.  D layout: col(lane&15)=c-frag, row=g*4+j
  float gm = gamma[0];
  int rowsub = g * 4;
#pragma unroll
  for (int mf = 0; mf < 2; ++mf) {
#pragma unroll
    for (int cf = 0; cf < 4; ++cf) {
      int c = c0 + cf * 16 + rsel;
      int nrow = n0 + mf * 16 + rowsub;
      const float4 xv = *(const float4*)(x + ((size_t)(b * C_ + c)) * N_ + nrow);
      float4 o;
      o.x = gm * acc[mf][cf][0] + xv.x;
      o.y = gm * acc[mf][cf][1] + xv.y;
      o.z = gm * acc[mf][cf][2] + xv.z;
      o.w = gm * acc[mf][cf][3] + xv.w;
      *(float4*)(out_g + ((size_t)(b * C_ + c)) * N_ + nrow) = o;
    }
  }
}

extern "C" void kernel_launch(void* const* d_in, const int* in_sizes, int n_in,
                              void* d_out, int out_size, void* d_ws, size_t ws_size,
                              hipStream_t stream) {
  const float* x  = (const float*)d_in[0];
  const float* k  = (const float*)d_in[1];
  const float* q  = (const float*)d_in[2];
  const float* Wq = (const float*)d_in[3];
  const float* bq = (const float*)d_in[4];
  const float* Wk = (const float*)d_in[5];
  const float* bk = (const float*)d_in[6];
  const float* Wv = (const float*)d_in[7];
  const float* bv = (const float*)d_in[8];
  const float* gamma = (const float*)d_in[9];

  float* out_g  = (float*)d_out;
  float* attn_g = out_g + (size_t)B_ * C_ * N_;  // attention starts after out

  // workspace layout (~9.2 MB): pq 512KB | pk 512KB | pv 8MB
  char* ws = (char*)d_ws;
  float* pq_g = (float*)ws;
  float* pk_g = (float*)(ws + (1u << 19));
  unsigned short* pv_g = (unsigned short*)(ws + (1u << 20));

  k_pqk<<<dim3(64, B_), 256, 0, stream>>>(q, k, Wq, bq, Wk, bk, pq_g, pk_g);
  k_pv<<<dim3(64, B_), 256, 0, stream>>>(x, Wv, bv, pv_g);
  k_attn<<<dim3(2048), 256, 0, stream>>>(pq_g, pk_g, attn_g);
  k_out<<<dim3(512), 256, 0, stream>>>(attn_g, pv_g, x, gamma, out_g);
}

// Round 12
// 224.628 us; speedup vs baseline: 2.9738x; 1.8672x over previous
//
#include <hip/hip_runtime.h>

// Problem constants (fixed by setup_inputs)
#define B_ 4
#define C_ 256
#define N_ 4096   // 64*64 spatial
#define D_ 8      // QK_DIM

typedef float f32x4 __attribute__((ext_vector_type(4)));
typedef __bf16 bf16x8 __attribute__((ext_vector_type(8)));

union U16 {
  bf16x8 v;
  unsigned short u[8];
  uint4 q;
};

__device__ inline unsigned short f2bf(float f) {
  unsigned int u = __float_as_uint(f);
  u = (u + 0x7FFFu + ((u >> 16) & 1u)) >> 16;  // RNE
  return (unsigned short)u;
}

#define AS1 __attribute__((address_space(1)))
#define AS3 __attribute__((address_space(3)))
__device__ __forceinline__ void g2l16(const void* g, void* l) {
  // async global->LDS DMA, 16B/lane; LDS dest = wave-uniform base + lane*16
  __builtin_amdgcn_global_load_lds((AS1 const void*)g, (AS3 void*)l, 16, 0, 0);
}

// ---------------------------------------------------------------------------
// K1: pq[b][n][d] = Wq[d,:]·q[b,:,n] + bq[d]   (B,N,8) d-contiguous
//     pk[b][d][n] = Wk[d,:]·k[b,:,n] + bk[d]   (B,8,N) n-contiguous
// ---------------------------------------------------------------------------
__global__ void __launch_bounds__(256) k_pqk(
    const float* __restrict__ q, const float* __restrict__ k,
    const float* __restrict__ Wq, const float* __restrict__ bq,
    const float* __restrict__ Wk, const float* __restrict__ bk,
    float* __restrict__ pq_g, float* __restrict__ pk_g) {
  int b = blockIdx.y, n0 = blockIdx.x * 64;
  int t = threadIdx.x, nl = t & 63, sub = t >> 6;  // sub uniform per wave
  int n = n0 + nl;
  float aq[D_], ak[D_];
#pragma unroll
  for (int d = 0; d < D_; ++d) { aq[d] = 0.f; ak[d] = 0.f; }
  const float* qp = q + ((size_t)(b * C_ + sub * 64)) * N_ + n;
  const float* kp = k + ((size_t)(b * C_ + sub * 64)) * N_ + n;
  for (int cc = 0; cc < 64; ++cc) {
    int c = sub * 64 + cc;
    float qv = qp[(size_t)cc * N_];
    float kv = kp[(size_t)cc * N_];
#pragma unroll
    for (int d = 0; d < D_; ++d) {
      aq[d] = fmaf(Wq[d * C_ + c], qv, aq[d]);
      ak[d] = fmaf(Wk[d * C_ + c], kv, ak[d]);
    }
  }
  __shared__ float red[4][64][16];
#pragma unroll
  for (int d = 0; d < D_; ++d) { red[sub][nl][d] = aq[d]; red[sub][nl][8 + d] = ak[d]; }
  __syncthreads();
  if (t < 64) {
#pragma unroll
    for (int d = 0; d < D_; ++d) {
      float s = red[0][t][d] + red[1][t][d] + red[2][t][d] + red[3][t][d] + bq[d];
      pq_g[((size_t)b * N_ + n0 + t) * D_ + d] = s;
      float s2 = red[0][t][8 + d] + red[1][t][8 + d] + red[2][t][8 + d] + red[3][t][8 + d] + bk[d];
      pk_g[((size_t)b * D_ + d) * N_ + n0 + t] = s2;
    }
  }
}

// ---------------------------------------------------------------------------
// K2: pv[b][e][n] = Wv[e,:]·x[b,:,n] + bv[e], stored bf16 in (B,C,N).
// ---------------------------------------------------------------------------
__global__ void __launch_bounds__(256) k_pv(
    const float* __restrict__ x, const float* __restrict__ Wv,
    const float* __restrict__ bv, unsigned short* __restrict__ pv_g) {
  int b = blockIdx.y, n0 = blockIdx.x * 64;
  int t = threadIdx.x, lane = t & 63, w = t >> 6;
  __shared__ unsigned short xs[64][264];  // [n][c]
  {
    int nl = t & 63, sub = t >> 6;
    for (int i = 0; i < 64; ++i) {
      int c = i * 4 + sub;
      float xv = x[((size_t)(b * C_ + c)) * N_ + n0 + nl];
      xs[nl][c] = f2bf(xv);
    }
  }
  __syncthreads();
  int e0 = w * 64;
  f32x4 acc[4][4];
#pragma unroll
  for (int mf = 0; mf < 4; ++mf)
#pragma unroll
    for (int nf = 0; nf < 4; ++nf) acc[mf][nf] = (f32x4)0.f;

  int rsel = lane & 15, koff = (lane >> 4) * 8;
  for (int kc = 0; kc < 8; ++kc) {
    int cbase = kc * 32 + koff;
    U16 afr[4];
#pragma unroll
    for (int mf = 0; mf < 4; ++mf) {
      const float* wp = Wv + (size_t)(e0 + mf * 16 + rsel) * C_ + cbase;
      float4 w0 = *(const float4*)wp;
      float4 w1 = *(const float4*)(wp + 4);
      afr[mf].u[0] = f2bf(w0.x); afr[mf].u[1] = f2bf(w0.y);
      afr[mf].u[2] = f2bf(w0.z); afr[mf].u[3] = f2bf(w0.w);
      afr[mf].u[4] = f2bf(w1.x); afr[mf].u[5] = f2bf(w1.y);
      afr[mf].u[6] = f2bf(w1.z); afr[mf].u[7] = f2bf(w1.w);
    }
    U16 bfr[4];
#pragma unroll
    for (int nf = 0; nf < 4; ++nf)
      bfr[nf].q = *(const uint4*)&xs[nf * 16 + rsel][cbase];
#pragma unroll
    for (int mf = 0; mf < 4; ++mf)
#pragma unroll
      for (int nf = 0; nf < 4; ++nf)
        acc[mf][nf] = __builtin_amdgcn_mfma_f32_16x16x32_bf16(afr[mf].v, bfr[nf].v, acc[mf][nf], 0, 0, 0);
  }
  int rowsub = (lane >> 4) * 4;
#pragma unroll
  for (int mf = 0; mf < 4; ++mf) {
#pragma unroll
    for (int nf = 0; nf < 4; ++nf) {
      int n = n0 + nf * 16 + rsel;
#pragma unroll
      for (int j = 0; j < 4; ++j) {
        int e = e0 + mf * 16 + rowsub + j;
        float v = acc[mf][nf][j] + bv[e];
        pv_g[((size_t)(b * C_ + e)) * N_ + n] = f2bf(v);
      }
    }
  }
}

// ---------------------------------------------------------------------------
// K3 (fused rowsum + attention store): block = 8 rows x full m; wave w owns
// m-quarter. Two passes, no barriers in m loops. Near write-BW (~54us).
// ---------------------------------------------------------------------------
__global__ void __launch_bounds__(256, 4) k_attn(
    const float* __restrict__ pq_g, const float* __restrict__ pk_g,
    float* __restrict__ attn_g) {
  int bx = blockIdx.x;
  int b = bx & 3;
  int rg = bx >> 2;            // 0..511
  int r0 = rg * 8;
  int t = threadIdx.x, lane = t & 63, w = t >> 6;
  int mq = w * 1024;           // wave's m-quarter

  float pqr[8][D_];
#pragma unroll
  for (int rr = 0; rr < 8; ++rr) {
    const float4* pp = (const float4*)(pq_g + ((size_t)b * N_ + r0 + rr) * D_);
    float4 a = pp[0], c4 = pp[1];
    pqr[rr][0] = a.x; pqr[rr][1] = a.y; pqr[rr][2] = a.z; pqr[rr][3] = a.w;
    pqr[rr][4] = c4.x; pqr[rr][5] = c4.y; pqr[rr][6] = c4.z; pqr[rr][7] = c4.w;
  }
  const float* pkb = pk_g + (size_t)b * D_ * N_;

  // ---- pass 1: partial rowsums over this wave's quarter ----
  float s[8];
#pragma unroll
  for (int rr = 0; rr < 8; ++rr) s[rr] = 0.f;
  for (int tt = 0; tt < 16; ++tt) {
    int m = mq + tt * 64 + lane;
    float pkr[D_];
#pragma unroll
    for (int d = 0; d < D_; ++d) pkr[d] = pkb[(size_t)d * N_ + m];
#pragma unroll
    for (int rr = 0; rr < 8; ++rr) {
      float e = pqr[rr][0] * pkr[0];
#pragma unroll
      for (int d = 1; d < D_; ++d) e = fmaf(pqr[rr][d], pkr[d], e);
      s[rr] += __expf(e);
    }
  }
#pragma unroll
  for (int rr = 0; rr < 8; ++rr) {
    float v = s[rr];
    for (int off = 32; off; off >>= 1) v += __shfl_xor(v, off);
    s[rr] = v;
  }
  __shared__ float red[4][8];
  if (lane == 0) {
#pragma unroll
    for (int rr = 0; rr < 8; ++rr) red[w][rr] = s[rr];
  }
  __syncthreads();
  float rinv[8];
#pragma unroll
  for (int rr = 0; rr < 8; ++rr)
    rinv[rr] = 1.0f / (red[0][rr] + red[1][rr] + red[2][rr] + red[3][rr]);

  // ---- pass 2: normalize + NT store (coalesced 256B/row-instruction) ----
  float* attb = attn_g + ((size_t)b * N_ + r0) * N_;
  for (int tt = 0; tt < 16; ++tt) {
    int m = mq + tt * 64 + lane;
    float pkr[D_];
#pragma unroll
    for (int d = 0; d < D_; ++d) pkr[d] = pkb[(size_t)d * N_ + m];
#pragma unroll
    for (int rr = 0; rr < 8; ++rr) {
      float e = pqr[rr][0] * pkr[0];
#pragma unroll
      for (int d = 1; d < D_; ++d) e = fmaf(pqr[rr][d], pkr[d], e);
      float a = __expf(e) * rinv[rr];
      __builtin_nontemporal_store(a, attb + (size_t)rr * N_ + m);
    }
  }
}

// ---------------------------------------------------------------------------
// K4 (GEMM, T3 2-phase pipeline): out[b][c][n] = gamma*sum_m pv[c][m]*
// attn[n][m] + x[c][n]. Both operands staged via global_load_lds DMA
// (double-buffered), raw s_barrier + counted vmcnt placed AFTER the MFMA so
// DMA latency hides under compute — no __syncthreads full-drain per iter
// (the round-6/9 stall). pv source pre-XOR-swizzled per lane (LDS linear);
// attn fp32 source swizzled in 32B slots, cvt->bf16 after ds_read.
// Block = 32 n x 256 c, 4 waves (wave w: c-slice w*64 = its staged pv rows).
// grid 512 = 4b x 128 groups; b = bx&3 pins pv(b)+attn rows per XCD-pair.
// ---------------------------------------------------------------------------
__global__ void __launch_bounds__(256, 2) k_out(
    const float* __restrict__ attn_g, const unsigned short* __restrict__ pv_g,
    const float* __restrict__ x, const float* __restrict__ gamma,
    float* __restrict__ out_g) {
  int bx = blockIdx.x;
  int b = bx & 3, grp = bx >> 2;
  int n0 = grp * 32;
  int t = threadIdx.x, lane = t & 63, w = t >> 6;
  int rsel = lane & 15, g = lane >> 4;
  int c0 = w * 64;

  __shared__ unsigned short pvs[2][256][64];  // 64KB, slot-swizzled content
  __shared__ float asl[2][32][64];            // 16KB fp32 attn, slot-swizzled

  const unsigned short* pvb = pv_g + (size_t)b * C_ * N_;
  const float* attb = attn_g + ((size_t)b * N_ + n0) * N_;

  f32x4 acc[2][4];
#pragma unroll
  for (int mf = 0; mf < 2; ++mf)
#pragma unroll
    for (int cf = 0; cf < 4; ++cf) acc[mf][cf] = (f32x4)0.f;

  // STAGE: issue 10 DMA per wave into buffer dstbuf for m-tile at M0.
  // pv: wave w's 64 c-rows; lane l -> row c0+i*8+(l>>3), 16B seg (l&7),
  //     source seg XOR (c&7)  (LDS linear, content swizzled).
  // attn: wave w rows w*8..+8 fp32; lane l -> row +(l>>4), granule l&15;
  //     source 32B-slot XOR (row&7).
#define STAGE(dstbuf, M0)                                                     \
  {                                                                           \
    _Pragma("unroll")                                                         \
    for (int i = 0; i < 8; ++i) {                                             \
      int c = c0 + i * 8 + (lane >> 3);                                       \
      int seg = lane & 7;                                                     \
      g2l16(pvb + (size_t)c * N_ + (M0) + ((seg ^ (c & 7)) << 3),             \
            &pvs[dstbuf][c0 + i * 8][0]);                                     \
    }                                                                         \
    _Pragma("unroll")                                                         \
    for (int j = 0; j < 2; ++j) {                                             \
      int row = w * 8 + j * 4 + (lane >> 4);                                  \
      int g16 = lane & 15;                                                    \
      int sslot = (g16 >> 1) ^ (row & 7);                                     \
      g2l16(attb + (size_t)row * N_ + (M0) + sslot * 8 + (g16 & 1) * 4,       \
            &asl[dstbuf][w * 8 + j * 4][0]);                                  \
    }                                                                         \
  }

  // prologue: stage tile 0 into buffer 0
  STAGE(0, 0)
  asm volatile("s_waitcnt vmcnt(0)" ::: "memory");
  __builtin_amdgcn_s_barrier();

  int cur = 0;
  for (int tt = 0; tt < 64; ++tt) {
    // ---- issue next-tile DMAs into the other buffer ----
    if (tt < 63) STAGE(cur ^ 1, (tt + 1) * 64)
    // ---- compute from buffer cur ----
    U16 afr[2][2], bfr[2][4];
#pragma unroll
    for (int kf = 0; kf < 2; ++kf) {
#pragma unroll
      for (int mf = 0; mf < 2; ++mf) {
        int row = mf * 16 + rsel;
        int ss2 = (kf * 4 + g) ^ (row & 7);
        const float* ap2 = &asl[cur][row][ss2 * 8];
        f32x4 a0 = *(const f32x4*)ap2;
        f32x4 a1 = *(const f32x4*)(ap2 + 4);
#pragma unroll
        for (int j = 0; j < 4; ++j) {
          afr[kf][mf].u[j] = f2bf(a0[j]);
          afr[kf][mf].u[4 + j] = f2bf(a1[j]);
        }
      }
#pragma unroll
      for (int cf = 0; cf < 4; ++cf) {
        int c = c0 + cf * 16 + rsel;
        int sg = kf * 4 + g;
        bfr[kf][cf].q = *(const uint4*)&pvs[cur][c][(sg ^ (c & 7)) * 8];
      }
    }
#pragma unroll
    for (int kf = 0; kf < 2; ++kf)
#pragma unroll
      for (int mf = 0; mf < 2; ++mf)
#pragma unroll
        for (int cf = 0; cf < 4; ++cf)
          acc[mf][cf] = __builtin_amdgcn_mfma_f32_16x16x32_bf16(
              afr[kf][mf].v, bfr[kf][cf].v, acc[mf][cf], 0, 0, 0);
    // ---- drain DMAs (hidden under the compute above) + publish ----
    asm volatile("s_waitcnt vmcnt(0) lgkmcnt(0)" ::: "memory");
    __builtin_amdgcn_s_barrier();
    cur ^= 1;
  }
#undef STAGE
  // epilogue: out = gamma*acc + x.  D layout: col(lane&15)=c-frag, row=g*4+j
  float gm = gamma[0];
  int rowsub = g * 4;
#pragma unroll
  for (int mf = 0; mf < 2; ++mf) {
#pragma unroll
    for (int cf = 0; cf < 4; ++cf) {
      int c = c0 + cf * 16 + rsel;
      int nrow = n0 + mf * 16 + rowsub;
      const float4 xv = *(const float4*)(x + ((size_t)(b * C_ + c)) * N_ + nrow);
      float4 o;
      o.x = gm * acc[mf][cf][0] + xv.x;
      o.y = gm * acc[mf][cf][1] + xv.y;
      o.z = gm * acc[mf][cf][2] + xv.z;
      o.w = gm * acc[mf][cf][3] + xv.w;
      *(float4*)(out_g + ((size_t)(b * C_ + c)) * N_ + nrow) = o;
    }
  }
}

extern "C" void kernel_launch(void* const* d_in, const int* in_sizes, int n_in,
                              void* d_out, int out_size, void* d_ws, size_t ws_size,
                              hipStream_t stream) {
  const float* x  = (const float*)d_in[0];
  const float* k  = (const float*)d_in[1];
  const float* q  = (const float*)d_in[2];
  const float* Wq = (const float*)d_in[3];
  const float* bq = (const float*)d_in[4];
  const float* Wk = (const float*)d_in[5];
  const float* bk = (const float*)d_in[6];
  const float* Wv = (const float*)d_in[7];
  const float* bv = (const float*)d_in[8];
  const float* gamma = (const float*)d_in[9];

  float* out_g  = (float*)d_out;
  float* attn_g = out_g + (size_t)B_ * C_ * N_;  // attention starts after out

  // workspace layout (~9.2 MB): pq 512KB | pk 512KB | pv 8MB
  char* ws = (char*)d_ws;
  float* pq_g = (float*)ws;
  float* pk_g = (float*)(ws + (1u << 19));
  unsigned short* pv_g = (unsigned short*)(ws + (1u << 20));

  k_pqk<<<dim3(64, B_), 256, 0, stream>>>(q, k, Wq, bq, Wk, bk, pq_g, pk_g);
  k_pv<<<dim3(64, B_), 256, 0, stream>>>(x, Wv, bv, pv_g);
  k_attn<<<dim3(2048), 256, 0, stream>>>(pq_g, pk_g, attn_g);
  k_out<<<dim3(512), 256, 0, stream>>>(attn_g, pv_g, x, gamma, out_g);
}

// Round 14
// 196.227 us; speedup vs baseline: 3.4042x; 1.1447x over previous
//
#include <hip/hip_runtime.h>

// Problem constants (fixed by setup_inputs)
#define B_ 4
#define C_ 256
#define N_ 4096   // 64*64 spatial
#define D_ 8      // QK_DIM

typedef float f32x4 __attribute__((ext_vector_type(4)));
typedef __bf16 bf16x8 __attribute__((ext_vector_type(8)));

union U16 {
  bf16x8 v;
  unsigned short u[8];
  uint4 q;
};

__device__ inline unsigned short f2bf(float f) {
  unsigned int u = __float_as_uint(f);
  u = (u + 0x7FFFu + ((u >> 16) & 1u)) >> 16;  // RNE
  return (unsigned short)u;
}

#define AS1 __attribute__((address_space(1)))
#define AS3 __attribute__((address_space(3)))
__device__ __forceinline__ void g2l16(const void* g, void* l) {
  // async global->LDS DMA, 16B/lane; LDS dest = wave-uniform base + lane*16
  __builtin_amdgcn_global_load_lds((AS1 const void*)g, (AS3 void*)l, 16, 0, 0);
}

// ---------------------------------------------------------------------------
// K1: pq[b][n][d] = Wq[d,:]·q[b,:,n] + bq[d]   (B,N,8) d-contiguous
//     pk[b][d][n] = Wk[d,:]·k[b,:,n] + bk[d]   (B,8,N) n-contiguous
// ---------------------------------------------------------------------------
__global__ void __launch_bounds__(256) k_pqk(
    const float* __restrict__ q, const float* __restrict__ k,
    const float* __restrict__ Wq, const float* __restrict__ bq,
    const float* __restrict__ Wk, const float* __restrict__ bk,
    float* __restrict__ pq_g, float* __restrict__ pk_g) {
  int b = blockIdx.y, n0 = blockIdx.x * 64;
  int t = threadIdx.x, nl = t & 63, sub = t >> 6;  // sub uniform per wave
  int n = n0 + nl;
  float aq[D_], ak[D_];
#pragma unroll
  for (int d = 0; d < D_; ++d) { aq[d] = 0.f; ak[d] = 0.f; }
  const float* qp = q + ((size_t)(b * C_ + sub * 64)) * N_ + n;
  const float* kp = k + ((size_t)(b * C_ + sub * 64)) * N_ + n;
  for (int cc = 0; cc < 64; ++cc) {
    int c = sub * 64 + cc;
    float qv = qp[(size_t)cc * N_];
    float kv = kp[(size_t)cc * N_];
#pragma unroll
    for (int d = 0; d < D_; ++d) {
      aq[d] = fmaf(Wq[d * C_ + c], qv, aq[d]);
      ak[d] = fmaf(Wk[d * C_ + c], kv, ak[d]);
    }
  }
  __shared__ float red[4][64][16];
#pragma unroll
  for (int d = 0; d < D_; ++d) { red[sub][nl][d] = aq[d]; red[sub][nl][8 + d] = ak[d]; }
  __syncthreads();
  if (t < 64) {
#pragma unroll
    for (int d = 0; d < D_; ++d) {
      float s = red[0][t][d] + red[1][t][d] + red[2][t][d] + red[3][t][d] + bq[d];
      pq_g[((size_t)b * N_ + n0 + t) * D_ + d] = s;
      float s2 = red[0][t][8 + d] + red[1][t][8 + d] + red[2][t][8 + d] + red[3][t][8 + d] + bk[d];
      pk_g[((size_t)b * D_ + d) * N_ + n0 + t] = s2;
    }
  }
}

// ---------------------------------------------------------------------------
// K2: pv[b][e][n] = Wv[e,:]·x[b,:,n] + bv[e], stored bf16 in (B,C,N).
// ---------------------------------------------------------------------------
__global__ void __launch_bounds__(256) k_pv(
    const float* __restrict__ x, const float* __restrict__ Wv,
    const float* __restrict__ bv, unsigned short* __restrict__ pv_g) {
  int b = blockIdx.y, n0 = blockIdx.x * 64;
  int t = threadIdx.x, lane = t & 63, w = t >> 6;
  __shared__ unsigned short xs[64][264];  // [n][c]
  {
    int nl = t & 63, sub = t >> 6;
    for (int i = 0; i < 64; ++i) {
      int c = i * 4 + sub;
      float xv = x[((size_t)(b * C_ + c)) * N_ + n0 + nl];
      xs[nl][c] = f2bf(xv);
    }
  }
  __syncthreads();
  int e0 = w * 64;
  f32x4 acc[4][4];
#pragma unroll
  for (int mf = 0; mf < 4; ++mf)
#pragma unroll
    for (int nf = 0; nf < 4; ++nf) acc[mf][nf] = (f32x4)0.f;

  int rsel = lane & 15, koff = (lane >> 4) * 8;
  for (int kc = 0; kc < 8; ++kc) {
    int cbase = kc * 32 + koff;
    U16 afr[4];
#pragma unroll
    for (int mf = 0; mf < 4; ++mf) {
      const float* wp = Wv + (size_t)(e0 + mf * 16 + rsel) * C_ + cbase;
      float4 w0 = *(const float4*)wp;
      float4 w1 = *(const float4*)(wp + 4);
      afr[mf].u[0] = f2bf(w0.x); afr[mf].u[1] = f2bf(w0.y);
      afr[mf].u[2] = f2bf(w0.z); afr[mf].u[3] = f2bf(w0.w);
      afr[mf].u[4] = f2bf(w1.x); afr[mf].u[5] = f2bf(w1.y);
      afr[mf].u[6] = f2bf(w1.z); afr[mf].u[7] = f2bf(w1.w);
    }
    U16 bfr[4];
#pragma unroll
    for (int nf = 0; nf < 4; ++nf)
      bfr[nf].q = *(const uint4*)&xs[nf * 16 + rsel][cbase];
#pragma unroll
    for (int mf = 0; mf < 4; ++mf)
#pragma unroll
      for (int nf = 0; nf < 4; ++nf)
        acc[mf][nf] = __builtin_amdgcn_mfma_f32_16x16x32_bf16(afr[mf].v, bfr[nf].v, acc[mf][nf], 0, 0, 0);
  }
  int rowsub = (lane >> 4) * 4;
#pragma unroll
  for (int mf = 0; mf < 4; ++mf) {
#pragma unroll
    for (int nf = 0; nf < 4; ++nf) {
      int n = n0 + nf * 16 + rsel;
#pragma unroll
      for (int j = 0; j < 4; ++j) {
        int e = e0 + mf * 16 + rowsub + j;
        float v = acc[mf][nf][j] + bv[e];
        pv_g[((size_t)(b * C_ + e)) * N_ + n] = f2bf(v);
      }
    }
  }
}

// ---------------------------------------------------------------------------
// K3 (fused rowsum + attention store): block = 8 rows x full m; wave w owns
// m-quarter. Two passes, no barriers in m loops. Near write-BW (~54us).
// ---------------------------------------------------------------------------
__global__ void __launch_bounds__(256, 4) k_attn(
    const float* __restrict__ pq_g, const float* __restrict__ pk_g,
    float* __restrict__ attn_g) {
  int bx = blockIdx.x;
  int b = bx & 3;
  int rg = bx >> 2;            // 0..511
  int r0 = rg * 8;
  int t = threadIdx.x, lane = t & 63, w = t >> 6;
  int mq = w * 1024;           // wave's m-quarter

  float pqr[8][D_];
#pragma unroll
  for (int rr = 0; rr < 8; ++rr) {
    const float4* pp = (const float4*)(pq_g + ((size_t)b * N_ + r0 + rr) * D_);
    float4 a = pp[0], c4 = pp[1];
    pqr[rr][0] = a.x; pqr[rr][1] = a.y; pqr[rr][2] = a.z; pqr[rr][3] = a.w;
    pqr[rr][4] = c4.x; pqr[rr][5] = c4.y; pqr[rr][6] = c4.z; pqr[rr][7] = c4.w;
  }
  const float* pkb = pk_g + (size_t)b * D_ * N_;

  // ---- pass 1: partial rowsums over this wave's quarter ----
  float s[8];
#pragma unroll
  for (int rr = 0; rr < 8; ++rr) s[rr] = 0.f;
  for (int tt = 0; tt < 16; ++tt) {
    int m = mq + tt * 64 + lane;
    float pkr[D_];
#pragma unroll
    for (int d = 0; d < D_; ++d) pkr[d] = pkb[(size_t)d * N_ + m];
#pragma unroll
    for (int rr = 0; rr < 8; ++rr) {
      float e = pqr[rr][0] * pkr[0];
#pragma unroll
      for (int d = 1; d < D_; ++d) e = fmaf(pqr[rr][d], pkr[d], e);
      s[rr] += __expf(e);
    }
  }
#pragma unroll
  for (int rr = 0; rr < 8; ++rr) {
    float v = s[rr];
    for (int off = 32; off; off >>= 1) v += __shfl_xor(v, off);
    s[rr] = v;
  }
  __shared__ float red[4][8];
  if (lane == 0) {
#pragma unroll
    for (int rr = 0; rr < 8; ++rr) red[w][rr] = s[rr];
  }
  __syncthreads();
  float rinv[8];
#pragma unroll
  for (int rr = 0; rr < 8; ++rr)
    rinv[rr] = 1.0f / (red[0][rr] + red[1][rr] + red[2][rr] + red[3][rr]);

  // ---- pass 2: normalize + NT store (coalesced 256B/row-instruction) ----
  float* attb = attn_g + ((size_t)b * N_ + r0) * N_;
  for (int tt = 0; tt < 16; ++tt) {
    int m = mq + tt * 64 + lane;
    float pkr[D_];
#pragma unroll
    for (int d = 0; d < D_; ++d) pkr[d] = pkb[(size_t)d * N_ + m];
#pragma unroll
    for (int rr = 0; rr < 8; ++rr) {
      float e = pqr[rr][0] * pkr[0];
#pragma unroll
      for (int d = 1; d < D_; ++d) e = fmaf(pqr[rr][d], pkr[d], e);
      float a = __expf(e) * rinv[rr];
      __builtin_nontemporal_store(a, attb + (size_t)rr * N_ + m);
    }
  }
}

// ---------------------------------------------------------------------------
// K4 (GEMM, T3+T4: counted-vmcnt wait-BEFORE-compute): tile t's 10 DMAs/wave
// were issued one iteration ago; at iter top we issue tile t+1's 10, then
// s_waitcnt vmcnt(10) waits only the OLDEST 10 (tile t) — tile t+1's stay in
// flight, so the HBM latency is hidden by a full iteration instead of being
// paid after compute (the round-12 residual stall).
// pv source pre-XOR-swizzled per lane (LDS linear); attn fp32 source
// swizzled in 32B slots, cvt->bf16 after ds_read.
// Block = 32 n x 256 c, 4 waves; grid 512 = 4b x 128 groups, b=bx&3.
// ---------------------------------------------------------------------------
__global__ void __launch_bounds__(256, 2) k_out(
    const float* __restrict__ attn_g, const unsigned short* __restrict__ pv_g,
    const float* __restrict__ x, const float* __restrict__ gamma,
    float* __restrict__ out_g) {
  int bx = blockIdx.x;
  int b = bx & 3, grp = bx >> 2;
  int n0 = grp * 32;
  int t = threadIdx.x, lane = t & 63, w = t >> 6;
  int rsel = lane & 15, g = lane >> 4;
  int c0 = w * 64;

  __shared__ unsigned short pvs[2][256][64];  // 64KB, slot-swizzled content
  __shared__ float asl[2][32][64];            // 16KB fp32 attn, slot-swizzled

  const unsigned short* pvb = pv_g + (size_t)b * C_ * N_;
  const float* attb = attn_g + ((size_t)b * N_ + n0) * N_;

  f32x4 acc[2][4];
#pragma unroll
  for (int mf = 0; mf < 2; ++mf)
#pragma unroll
    for (int cf = 0; cf < 4; ++cf) acc[mf][cf] = (f32x4)0.f;

  // STAGE: issue 10 DMA per wave into buffer dstbuf for m-tile at M0.
#define STAGE(dstbuf, M0)                                                     \
  {                                                                           \
    _Pragma("unroll")                                                         \
    for (int i = 0; i < 8; ++i) {                                             \
      int c = c0 + i * 8 + (lane >> 3);                                       \
      int seg = lane & 7;                                                     \
      g2l16(pvb + (size_t)c * N_ + (M0) + ((seg ^ (c & 7)) << 3),             \
            &pvs[dstbuf][c0 + i * 8][0]);                                     \
    }                                                                         \
    _Pragma("unroll")                                                         \
    for (int j = 0; j < 2; ++j) {                                             \
      int row = w * 8 + j * 4 + (lane >> 4);                                  \
      int g16 = lane & 15;                                                    \
      int sslot = (g16 >> 1) ^ (row & 7);                                     \
      g2l16(attb + (size_t)row * N_ + (M0) + sslot * 8 + (g16 & 1) * 4,       \
            &asl[dstbuf][w * 8 + j * 4][0]);                                  \
    }                                                                         \
  }

  // prologue: issue tile 0 into buffer 0 (no drain — iter 0's wait handles it)
  STAGE(0, 0)

  int cur = 0;
  for (int tt = 0; tt < 64; ++tt) {
    // ---- issue next-tile DMAs, then wait only for the CURRENT tile ----
    if (tt < 63) {
      STAGE(cur ^ 1, (tt + 1) * 64)
      asm volatile("s_waitcnt vmcnt(10)" ::: "memory");  // oldest 10 = tile tt
    } else {
      asm volatile("s_waitcnt vmcnt(0)" ::: "memory");   // last tile: drain
    }
    __builtin_amdgcn_s_barrier();  // all waves' tile-tt data visible
    // ---- compute from buffer cur ----
    U16 afr[2][2], bfr[2][4];
#pragma unroll
    for (int kf = 0; kf < 2; ++kf) {
#pragma unroll
      for (int mf = 0; mf < 2; ++mf) {
        int row = mf * 16 + rsel;
        int ss2 = (kf * 4 + g) ^ (row & 7);
        const float* ap2 = &asl[cur][row][ss2 * 8];
        f32x4 a0 = *(const f32x4*)ap2;
        f32x4 a1 = *(const f32x4*)(ap2 + 4);
#pragma unroll
        for (int j = 0; j < 4; ++j) {
          afr[kf][mf].u[j] = f2bf(a0[j]);
          afr[kf][mf].u[4 + j] = f2bf(a1[j]);
        }
      }
#pragma unroll
      for (int cf = 0; cf < 4; ++cf) {
        int c = c0 + cf * 16 + rsel;
        int sg = kf * 4 + g;
        bfr[kf][cf].q = *(const uint4*)&pvs[cur][c][(sg ^ (c & 7)) * 8];
      }
    }
#pragma unroll
    for (int kf = 0; kf < 2; ++kf)
#pragma unroll
      for (int mf = 0; mf < 2; ++mf)
#pragma unroll
        for (int cf = 0; cf < 4; ++cf)
          acc[mf][cf] = __builtin_amdgcn_mfma_f32_16x16x32_bf16(
              afr[kf][mf].v, bfr[kf][cf].v, acc[mf][cf], 0, 0, 0);
    // ---- all waves done reading buf cur before it is re-staged next iter ----
    __builtin_amdgcn_s_barrier();
    cur ^= 1;
  }
#undef STAGE
  // epilogue: out = gamma*acc + x.  D layout: col(lane&15)=c-frag, row=g*4+j
  float gm = gamma[0];
  int rowsub = g * 4;
#pragma unroll
  for (int mf = 0; mf < 2; ++mf) {
#pragma unroll
    for (int cf = 0; cf < 4; ++cf) {
      int c = c0 + cf * 16 + rsel;
      int nrow = n0 + mf * 16 + rowsub;
      const float4 xv = *(const float4*)(x + ((size_t)(b * C_ + c)) * N_ + nrow);
      float4 o;
      o.x = gm * acc[mf][cf][0] + xv.x;
      o.y = gm * acc[mf][cf][1] + xv.y;
      o.z = gm * acc[mf][cf][2] + xv.z;
      o.w = gm * acc[mf][cf][3] + xv.w;
      *(float4*)(out_g + ((size_t)(b * C_ + c)) * N_ + nrow) = o;
    }
  }
}

extern "C" void kernel_launch(void* const* d_in, const int* in_sizes, int n_in,
                              void* d_out, int out_size, void* d_ws, size_t ws_size,
                              hipStream_t stream) {
  const float* x  = (const float*)d_in[0];
  const float* k  = (const float*)d_in[1];
  const float* q  = (const float*)d_in[2];
  const float* Wq = (const float*)d_in[3];
  const float* bq = (const float*)d_in[4];
  const float* Wk = (const float*)d_in[5];
  const float* bk = (const float*)d_in[6];
  const float* Wv = (const float*)d_in[7];
  const float* bv = (const float*)d_in[8];
  const float* gamma = (const float*)d_in[9];

  float* out_g  = (float*)d_out;
  float* attn_g = out_g + (size_t)B_ * C_ * N_;  // attention starts after out

  // workspace layout (~9.2 MB): pq 512KB | pk 512KB | pv 8MB
  char* ws = (char*)d_ws;
  float* pq_g = (float*)ws;
  float* pk_g = (float*)(ws + (1u << 19));
  unsigned short* pv_g = (unsigned short*)(ws + (1u << 20));

  k_pqk<<<dim3(64, B_), 256, 0, stream>>>(q, k, Wq, bq, Wk, bk, pq_g, pk_g);
  k_pv<<<dim3(64, B_), 256, 0, stream>>>(x, Wv, bv, pv_g);
  k_attn<<<dim3(2048), 256, 0, stream>>>(pq_g, pk_g, attn_g);
  k_out<<<dim3(512), 256, 0, stream>>>(attn_g, pv_g, x, gamma, out_g);
}

// Round 18
// 161.006 us; speedup vs baseline: 4.1490x; 1.2188x over previous
//
#include <hip/hip_runtime.h>

// Problem constants (fixed by setup_inputs)
#define B_ 4
#define C_ 256
#define N_ 4096   // 64*64 spatial
#define D_ 8      // QK_DIM

typedef float f32x4 __attribute__((ext_vector_type(4)));
typedef __bf16 bf16x8 __attribute__((ext_vector_type(8)));

union U16 {
  bf16x8 v;
  unsigned short u[8];
  uint4 q;
};

__device__ inline unsigned short f2bf(float f) {
  unsigned int u = __float_as_uint(f);
  u = (u + 0x7FFFu + ((u >> 16) & 1u)) >> 16;  // RNE
  return (unsigned short)u;
}

#define AS1 __attribute__((address_space(1)))
#define AS3 __attribute__((address_space(3)))
__device__ __forceinline__ void g2l16(const void* g, void* l) {
  // async global->LDS DMA, 16B/lane; LDS dest = wave-uniform base + lane*16
  __builtin_amdgcn_global_load_lds((AS1 const void*)g, (AS3 void*)l, 16, 0, 0);
}

// ---------------------------------------------------------------------------
// K1: pq[b][n][d] = Wq[d,:]·q[b,:,n] + bq[d]   (B,N,8) d-contiguous
//     pk[b][d][n] = Wk[d,:]·k[b,:,n] + bk[d]   (B,8,N) n-contiguous
// ---------------------------------------------------------------------------
__global__ void __launch_bounds__(256) k_pqk(
    const float* __restrict__ q, const float* __restrict__ k,
    const float* __restrict__ Wq, const float* __restrict__ bq,
    const float* __restrict__ Wk, const float* __restrict__ bk,
    float* __restrict__ pq_g, float* __restrict__ pk_g) {
  int b = blockIdx.y, n0 = blockIdx.x * 64;
  int t = threadIdx.x, nl = t & 63, sub = t >> 6;  // sub uniform per wave
  int n = n0 + nl;
  float aq[D_], ak[D_];
#pragma unroll
  for (int d = 0; d < D_; ++d) { aq[d] = 0.f; ak[d] = 0.f; }
  const float* qp = q + ((size_t)(b * C_ + sub * 64)) * N_ + n;
  const float* kp = k + ((size_t)(b * C_ + sub * 64)) * N_ + n;
  for (int cc = 0; cc < 64; ++cc) {
    int c = sub * 64 + cc;
    float qv = qp[(size_t)cc * N_];
    float kv = kp[(size_t)cc * N_];
#pragma unroll
    for (int d = 0; d < D_; ++d) {
      aq[d] = fmaf(Wq[d * C_ + c], qv, aq[d]);
      ak[d] = fmaf(Wk[d * C_ + c], kv, ak[d]);
    }
  }
  __shared__ float red[4][64][16];
#pragma unroll
  for (int d = 0; d < D_; ++d) { red[sub][nl][d] = aq[d]; red[sub][nl][8 + d] = ak[d]; }
  __syncthreads();
  if (t < 64) {
#pragma unroll
    for (int d = 0; d < D_; ++d) {
      float s = red[0][t][d] + red[1][t][d] + red[2][t][d] + red[3][t][d] + bq[d];
      pq_g[((size_t)b * N_ + n0 + t) * D_ + d] = s;
      float s2 = red[0][t][8 + d] + red[1][t][8 + d] + red[2][t][8 + d] + red[3][t][8 + d] + bk[d];
      pk_g[((size_t)b * D_ + d) * N_ + n0 + t] = s2;
    }
  }
}

// ---------------------------------------------------------------------------
// K2: pv[b][e][n] = Wv[e,:]·x[b,:,n] + bv[e], stored bf16 in (B,C,N).
// ---------------------------------------------------------------------------
__global__ void __launch_bounds__(256) k_pv(
    const float* __restrict__ x, const float* __restrict__ Wv,
    const float* __restrict__ bv, unsigned short* __restrict__ pv_g) {
  int b = blockIdx.y, n0 = blockIdx.x * 64;
  int t = threadIdx.x, lane = t & 63, w = t >> 6;
  __shared__ unsigned short xs[64][264];  // [n][c]
  {
    int nl = t & 63, sub = t >> 6;
    for (int i = 0; i < 64; ++i) {
      int c = i * 4 + sub;
      float xv = x[((size_t)(b * C_ + c)) * N_ + n0 + nl];
      xs[nl][c] = f2bf(xv);
    }
  }
  __syncthreads();
  int e0 = w * 64;
  f32x4 acc[4][4];
#pragma unroll
  for (int mf = 0; mf < 4; ++mf)
#pragma unroll
    for (int nf = 0; nf < 4; ++nf) acc[mf][nf] = (f32x4)0.f;

  int rsel = lane & 15, koff = (lane >> 4) * 8;
  for (int kc = 0; kc < 8; ++kc) {
    int cbase = kc * 32 + koff;
    U16 afr[4];
#pragma unroll
    for (int mf = 0; mf < 4; ++mf) {
      const float* wp = Wv + (size_t)(e0 + mf * 16 + rsel) * C_ + cbase;
      float4 w0 = *(const float4*)wp;
      float4 w1 = *(const float4*)(wp + 4);
      afr[mf].u[0] = f2bf(w0.x); afr[mf].u[1] = f2bf(w0.y);
      afr[mf].u[2] = f2bf(w0.z); afr[mf].u[3] = f2bf(w0.w);
      afr[mf].u[4] = f2bf(w1.x); afr[mf].u[5] = f2bf(w1.y);
      afr[mf].u[6] = f2bf(w1.z); afr[mf].u[7] = f2bf(w1.w);
    }
    U16 bfr[4];
#pragma unroll
    for (int nf = 0; nf < 4; ++nf)
      bfr[nf].q = *(const uint4*)&xs[nf * 16 + rsel][cbase];
#pragma unroll
    for (int mf = 0; mf < 4; ++mf)
#pragma unroll
      for (int nf = 0; nf < 4; ++nf)
        acc[mf][nf] = __builtin_amdgcn_mfma_f32_16x16x32_bf16(afr[mf].v, bfr[nf].v, acc[mf][nf], 0, 0, 0);
  }
  int rowsub = (lane >> 4) * 4;
#pragma unroll
  for (int mf = 0; mf < 4; ++mf) {
#pragma unroll
    for (int nf = 0; nf < 4; ++nf) {
      int n = n0 + nf * 16 + rsel;
#pragma unroll
      for (int j = 0; j < 4; ++j) {
        int e = e0 + mf * 16 + rowsub + j;
        float v = acc[mf][nf][j] + bv[e];
        pv_g[((size_t)(b * C_ + e)) * N_ + n] = f2bf(v);
      }
    }
  }
}

// ---------------------------------------------------------------------------
// K3: rinv[b][n] = 1 / sum_m exp(energy[b][n][m]).  (two-pass exact softmax;
// |e| <= ~13 so exp is fp32-safe without max subtraction)  [round-1 verified]
// ---------------------------------------------------------------------------
__global__ void __launch_bounds__(256) k_rowsum(
    const float* __restrict__ pq_g, const float* __restrict__ pk_g,
    float* __restrict__ rinv_g) {
  int b = blockIdx.y, n0 = blockIdx.x * 32;
  int t = threadIdx.x, lane = t & 63, w = t >> 6;
  int r0 = n0 + w * 8;
  float pqr[8][D_];
#pragma unroll
  for (int r = 0; r < 8; ++r) {
    const float4* pp = (const float4*)(pq_g + ((size_t)b * N_ + r0 + r) * D_);
    float4 a = pp[0], c4 = pp[1];
    pqr[r][0] = a.x; pqr[r][1] = a.y; pqr[r][2] = a.z; pqr[r][3] = a.w;
    pqr[r][4] = c4.x; pqr[r][5] = c4.y; pqr[r][6] = c4.z; pqr[r][7] = c4.w;
  }
  float s[8];
#pragma unroll
  for (int r = 0; r < 8; ++r) s[r] = 0.f;
  const float* pkb = pk_g + (size_t)b * D_ * N_;
  for (int tt = 0; tt < 64; ++tt) {
    int m = tt * 64 + lane;
    float pkr[D_];
#pragma unroll
    for (int d = 0; d < D_; ++d) pkr[d] = pkb[(size_t)d * N_ + m];
#pragma unroll
    for (int r = 0; r < 8; ++r) {
      float e = pqr[r][0] * pkr[0];
#pragma unroll
      for (int d = 1; d < D_; ++d) e = fmaf(pqr[r][d], pkr[d], e);
      s[r] += __expf(e);
    }
  }
#pragma unroll
  for (int r = 0; r < 8; ++r) {
    float v = s[r];
    for (int off = 32; off; off >>= 1) v += __shfl_xor(v, off);
    s[r] = v;
  }
  if (lane == 0) {
#pragma unroll
    for (int r = 0; r < 8; ++r) rinv_g[(size_t)b * N_ + r0 + r] = 1.0f / s[r];
  }
}

// ---------------------------------------------------------------------------
// K4 FUSED (attn compute + store + GEMM): eliminates the 268MB attention
// re-read of the split pipeline. Block = 32 n-rows x 256 c, 4 waves.
// Per m-tile (64): phase A: wave w computes attn rows w*8..+8 (lane=m),
// NT-stores fp32 attention + ds_writes bf16 to double-buffered asl.
// MFMA phase: 32n x 64c per wave from asl + DMA-staged pv (wave-private
// rows, XOR slot swizzle — verified r12/14). Pipelining: pv DMAs for tile
// t+1 issued at iter top; pk for tile t+1 prefetched to REGS — the
// compiler's wait at pk(t)'s first use drains exactly tile-t's DMAs while
// leaving tile-t+1's in flight (T4). One raw s_barrier + lgkmcnt(0)/iter;
// asl double-buffer + wave-private pvs make a second barrier unnecessary.
// grid 512 = 4b x 128 groups; b = bx&3 pins pv(b)+pk(b) per XCD-pair.
// ---------------------------------------------------------------------------
__global__ void __launch_bounds__(256, 2) k_fused(
    const float* __restrict__ pq_g, const float* __restrict__ pk_g,
    const float* __restrict__ rinv_g, const unsigned short* __restrict__ pv_g,
    const float* __restrict__ x, const float* __restrict__ gamma,
    float* __restrict__ out_g, float* __restrict__ attn_g) {
  int bx = blockIdx.x;
  int b = bx & 3, grp = bx >> 2;
  int n0 = grp * 32;
  int t = threadIdx.x, lane = t & 63, w = t >> 6;
  int rsel = lane & 15, g = lane >> 4, koff = g * 8;
  int c0 = w * 64;
  int r0 = n0 + w * 8;  // phase-A rows for this wave

  __shared__ unsigned short pvs[2][256][64];  // 64KB, slot-swizzled content
  __shared__ unsigned short asl[2][32][72];   // 9KB attn bf16, pad 72 (16B mult)

  // per-wave row data: pq rows + rinv
  float pqr[8][D_], rinv[8];
#pragma unroll
  for (int rr = 0; rr < 8; ++rr) {
    const float4* pp = (const float4*)(pq_g + ((size_t)b * N_ + r0 + rr) * D_);
    float4 a = pp[0], c4 = pp[1];
    pqr[rr][0] = a.x; pqr[rr][1] = a.y; pqr[rr][2] = a.z; pqr[rr][3] = a.w;
    pqr[rr][4] = c4.x; pqr[rr][5] = c4.y; pqr[rr][6] = c4.z; pqr[rr][7] = c4.w;
    rinv[rr] = rinv_g[(size_t)b * N_ + r0 + rr];
  }

  const float* pkb = pk_g + (size_t)b * D_ * N_;
  const unsigned short* pvb = pv_g + (size_t)b * C_ * N_;
  float* attb = attn_g + ((size_t)b * N_ + r0) * N_;

  f32x4 acc[2][4];
#pragma unroll
  for (int mf = 0; mf < 2; ++mf)
#pragma unroll
    for (int cf = 0; cf < 4; ++cf) acc[mf][cf] = (f32x4)0.f;

  // pv staging: wave w's 64 c-rows; LDS linear, source XOR-swizzled (verified)
#define STAGEPV(dstbuf, M0)                                                   \
  {                                                                           \
    _Pragma("unroll")                                                         \
    for (int i = 0; i < 8; ++i) {                                             \
      int c = c0 + i * 8 + (lane >> 3);                                       \
      int seg = lane & 7;                                                     \
      g2l16(pvb + (size_t)c * N_ + (M0) + ((seg ^ (c & 7)) << 3),             \
            &pvs[dstbuf][c0 + i * 8][0]);                                     \
    }                                                                         \
  }

  // prologue: tile 0 pv DMAs + tile 0 pk regs
  STAGEPV(0, 0)
  float pkr[D_];
#pragma unroll
  for (int d = 0; d < D_; ++d) pkr[d] = pkb[(size_t)d * N_ + lane];

  int cur = 0;
  for (int tt = 0; tt < 64; ++tt) {
    int m0 = tt * 64;
    bool more = (tt + 1 < 64);
    // ---- issue tile t+1: pv DMAs then pk reg loads ----
    if (more) STAGEPV(cur ^ 1, m0 + 64)
    float pkn[D_];
    if (more) {
#pragma unroll
      for (int d = 0; d < D_; ++d) pkn[d] = pkb[(size_t)d * N_ + m0 + 64 + lane];
    }
    // ---- phase A: attn rows r0..+8 at m=m0+lane (uses pkr -> compiler's
    //      vmcnt wait here drains tile-t DMAs, leaves tile-t+1 in flight) ----
#pragma unroll
    for (int rr = 0; rr < 8; ++rr) {
      float e = pqr[rr][0] * pkr[0];
#pragma unroll
      for (int d = 1; d < D_; ++d) e = fmaf(pqr[rr][d], pkr[d], e);
      float a = __expf(e) * rinv[rr];
      __builtin_nontemporal_store(a, attb + (size_t)rr * N_ + m0 + lane);
      asl[cur][w * 8 + rr][lane] = f2bf(a);
    }
    // publish asl writes to the block, then one barrier
    asm volatile("s_waitcnt lgkmcnt(0)" ::: "memory");
    __builtin_amdgcn_s_barrier();
    // ---- MFMA: 32 n x 64 c over K=64 from asl[cur] + pvs[cur] ----
    {
      U16 afr[2][2], bfr[2][4];
#pragma unroll
      for (int kf = 0; kf < 2; ++kf) {
#pragma unroll
        for (int mf = 0; mf < 2; ++mf)
          afr[kf][mf].q = *(const uint4*)&asl[cur][mf * 16 + rsel][kf * 32 + koff];
#pragma unroll
        for (int cf = 0; cf < 4; ++cf) {
          int c = c0 + cf * 16 + rsel;
          int sg = kf * 4 + g;
          bfr[kf][cf].q = *(const uint4*)&pvs[cur][c][(sg ^ (c & 7)) * 8];
        }
      }
#pragma unroll
      for (int kf = 0; kf < 2; ++kf)
#pragma unroll
        for (int mf = 0; mf < 2; ++mf)
#pragma unroll
          for (int cf = 0; cf < 4; ++cf)
            acc[mf][cf] = __builtin_amdgcn_mfma_f32_16x16x32_bf16(
                afr[kf][mf].v, bfr[kf][cf].v, acc[mf][cf], 0, 0, 0);
    }
#pragma unroll
    for (int d = 0; d < D_; ++d) pkr[d] = pkn[d];
    cur ^= 1;
  }
#undef STAGEPV
  // epilogue: out = gamma*acc + x.  D layout: col(lane&15)=c-frag, row=g*4+j
  float gm = gamma[0];
  int rowsub = g * 4;
#pragma unroll
  for (int mf = 0; mf < 2; ++mf) {
#pragma unroll
    for (int cf = 0; cf < 4; ++cf) {
      int c = c0 + cf * 16 + rsel;
      int nrow = n0 + mf * 16 + rowsub;
      const float4 xv = *(const float4*)(x + ((size_t)(b * C_ + c)) * N_ + nrow);
      float4 o;
      o.x = gm * acc[mf][cf][0] + xv.x;
      o.y = gm * acc[mf][cf][1] + xv.y;
      o.z = gm * acc[mf][cf][2] + xv.z;
      o.w = gm * acc[mf][cf][3] + xv.w;
      *(float4*)(out_g + ((size_t)(b * C_ + c)) * N_ + nrow) = o;
    }
  }
}

extern "C" void kernel_launch(void* const* d_in, const int* in_sizes, int n_in,
                              void* d_out, int out_size, void* d_ws, size_t ws_size,
                              hipStream_t stream) {
  const float* x  = (const float*)d_in[0];
  const float* k  = (const float*)d_in[1];
  const float* q  = (const float*)d_in[2];
  const float* Wq = (const float*)d_in[3];
  const float* bq = (const float*)d_in[4];
  const float* Wk = (const float*)d_in[5];
  const float* bk = (const float*)d_in[6];
  const float* Wv = (const float*)d_in[7];
  const float* bv = (const float*)d_in[8];
  const float* gamma = (const float*)d_in[9];

  float* out_g  = (float*)d_out;
  float* attn_g = out_g + (size_t)B_ * C_ * N_;  // attention starts after out

  // workspace layout (~9.2 MB): pq 512KB | pk 512KB | rinv 64KB | pv 8MB
  char* ws = (char*)d_ws;
  float* pq_g = (float*)ws;
  float* pk_g = (float*)(ws + (1u << 19));
  float* rinv_g = (float*)(ws + (1u << 20));
  unsigned short* pv_g = (unsigned short*)(ws + (1u << 20) + (1u << 17));

  k_pqk<<<dim3(64, B_), 256, 0, stream>>>(q, k, Wq, bq, Wk, bk, pq_g, pk_g);
  k_pv<<<dim3(64, B_), 256, 0, stream>>>(x, Wv, bv, pv_g);
  k_rowsum<<<dim3(128, B_), 256, 0, stream>>>(pq_g, pk_g, rinv_g);
  k_fused<<<dim3(512), 256, 0, stream>>>(pq_g, pk_g, rinv_g, pv_g, x, gamma, out_g, attn_g);
}